// Round 9
// baseline (192.779 us; speedup 1.0000x reference)
//
#include <hip/hip_runtime.h>
#include <math.h>

#define T_N 2097152
#define NB 2048                // blocks for k_summ / k_main
#define NT 256
#define EPT 4
#define CHUNK (NT * EPT)       // 1024 elements per block
#define GPT (NB / NT)          // 8 block-summaries per thread in k_carry
#define GAMMA_F 0.99f
#define GL_F (0.99f * 0.95f)
#define LOG2PI_F 1.8378770664093453f

// ws layout (every slot rewritten each launch -> poison-safe):
//   ws +      0 : float stats[4]  (mean_a, inv_a, mean_r, inv_r)
//   ws +    256 : float4 blk[NB*4]   extended block summaries (14 floats padded to 16)
//   ws + 131328 : float2 car[NB]     per-block entering carries (ret, adv)
//   ws + 147712 : float2 lblk[NB]    per-block loss partials (actor, critic)
//   ws + 164096 : float rat[T]       per-row importance ratio (8 MB)

// ---------------- affine (A,B) pair for both recurrences ----------------
struct Aff4 { float ar, br, aa, ba; };
__device__ __forceinline__ Aff4 aff_id() { Aff4 o; o.ar = 1.f; o.br = 0.f; o.aa = 1.f; o.ba = 0.f; return o; }
// L earlier in time (applied second in reverse scan): (L o R)(y) = L(R(y))
__device__ __forceinline__ Aff4 aff_compose(const Aff4& L, const Aff4& R) {
    Aff4 o;
    o.ar = L.ar * R.ar;  o.br = fmaf(L.ar, R.br, L.br);
    o.aa = L.aa * R.aa;  o.ba = fmaf(L.aa, R.ba, L.ba);
    return o;
}
__device__ __forceinline__ Aff4 aff_shfl_down(const Aff4& x, int s) {
    Aff4 o;
    o.ar = __shfl_down(x.ar, s, 64); o.br = __shfl_down(x.br, s, 64);
    o.aa = __shfl_down(x.aa, s, 64); o.ba = __shfl_down(x.ba, s, 64);
    return o;
}
__device__ __forceinline__ Aff4 aff_wave_suffix(Aff4 x, int lane) {
#pragma unroll
    for (int s = 1; s < 64; s <<= 1) {
        Aff4 o = aff_shfl_down(x, s);
        if (lane + s < 64) x = aff_compose(x, o);
    }
    return x;
}

// ------------- extended segment: y-map + running sum + running sum-of-squares -------------
// y_out = A*y + B ; Sum(y_t) = P*y + S ; Sum(y_t^2) = U*y^2 + 2*V*y + Q   (y = incoming state)
struct SegF { float A, B, P, S, U, V, Q; };
struct Seg2F { SegF r, a; };

__device__ __forceinline__ SegF segf_compose(const SegF& L, const SegF& R) {
    SegF o;
    o.A = L.A * R.A;
    o.B = fmaf(L.A, R.B, L.B);
    o.P = fmaf(L.P, R.A, R.P);
    o.S = fmaf(L.P, R.B, R.S) + L.S;
    float A2 = R.A * R.A, AB = R.A * R.B, B2 = R.B * R.B;
    o.U = fmaf(L.U, A2, R.U);
    o.V = fmaf(L.U, AB, fmaf(L.V, R.A, R.V));
    o.Q = fmaf(L.U, B2, fmaf(2.f * L.V, R.B, R.Q)) + L.Q;
    return o;
}
__device__ __forceinline__ Seg2F seg2f_compose(const Seg2F& L, const Seg2F& R) {
    Seg2F o; o.r = segf_compose(L.r, R.r); o.a = segf_compose(L.a, R.a); return o;
}
__device__ __forceinline__ SegF segf_shfl_down(const SegF& x, int s) {
    SegF o;
    o.A = __shfl_down(x.A, s, 64); o.B = __shfl_down(x.B, s, 64);
    o.P = __shfl_down(x.P, s, 64); o.S = __shfl_down(x.S, s, 64);
    o.U = __shfl_down(x.U, s, 64); o.V = __shfl_down(x.V, s, 64);
    o.Q = __shfl_down(x.Q, s, 64);
    return o;
}
__device__ __forceinline__ Seg2F seg2f_shfl_down(const Seg2F& x, int s) {
    Seg2F o; o.r = segf_shfl_down(x.r, s); o.a = segf_shfl_down(x.a, s); return o;
}
__device__ __forceinline__ Seg2F seg2f_id() {
    Seg2F o;
    o.r.A = 1.f; o.r.B = 0.f; o.r.P = 0.f; o.r.S = 0.f; o.r.U = 0.f; o.r.V = 0.f; o.r.Q = 0.f;
    o.a = o.r;
    return o;
}

__device__ __forceinline__ void load4(const float* __restrict__ rew,
                                      const float* __restrict__ val,
                                      const int* __restrict__ msk, int g,
                                      float rr[EPT], float vv[EPT], float mm[EPT],
                                      float& vnext) {
    float4 r4 = *(const float4*)(rew + g);
    float4 v4 = *(const float4*)(val + g);
    int4 m4 = *(const int4*)(msk + g);
    vnext = (g + EPT < T_N) ? val[g + EPT] : 0.f;
    rr[0] = r4.x; rr[1] = r4.y; rr[2] = r4.z; rr[3] = r4.w;
    vv[0] = v4.x; vv[1] = v4.y; vv[2] = v4.z; vv[3] = v4.w;
    mm[0] = (float)m4.x; mm[1] = (float)m4.y; mm[2] = (float)m4.z; mm[3] = (float)m4.w;
}

// ============ K1: streaming pass — extended block summaries + ratio materialization ============
__global__ __launch_bounds__(NT) void k_summ(const float* __restrict__ rew,
                                             const float* __restrict__ val,
                                             const int* __restrict__ msk,
                                             const float4* __restrict__ act,
                                             const float4* __restrict__ mu,
                                             const float4* __restrict__ lv,
                                             const float4* __restrict__ blp,
                                             float4* __restrict__ blk,
                                             float* __restrict__ rat) {
    int tid = threadIdx.x, lane = tid & 63, wv = tid >> 6;
    int b = blockIdx.x;
    int gbase = b * CHUNK;

    // ---- all loads issued up front (MLP): 16 loss float4 rows (lane-dense) + scan streams ----
    float4 A[4], M[4], L[4], B[4];
#pragma unroll
    for (int k = 0; k < 4; ++k) {
        int t = gbase + tid + k * NT;
        A[k] = act[t]; M[k] = mu[t]; L[k] = lv[t]; B[k] = blp[t];
    }
    int g = gbase + tid * EPT;
    float rr[EPT], vv[EPT], mm[EPT], vnext;
    load4(rew, val, msk, g, rr, vv, mm, vnext);

    // ---- ratio per loss row, stored lane-dense (coalesced dword stores) ----
#pragma unroll
    for (int k = 0; k < 4; ++k) {
        float4 a = A[k], m = M[k], l = L[k], bb = B[k];
        float x0 = -0.5f * (a.x - m.x) * (a.x - m.x) * expf(-l.x) - 0.5f * l.x;
        float x1 = -0.5f * (a.y - m.y) * (a.y - m.y) * expf(-l.y) - 0.5f * l.y;
        float x2 = -0.5f * (a.z - m.z) * (a.z - m.z) * expf(-l.z) - 0.5f * l.z;
        float x3 = -0.5f * (a.w - m.w) * (a.w - m.w) * expf(-l.w) - 0.5f * l.w;
        float X = (x0 + x1 + x2 + x3) - (bb.x + bb.y + bb.z + bb.w) - 2.f * LOG2PI_F;
        rat[gbase + tid + k * NT] = expf(X);
    }

    // ---- extended segment for this thread's 4 scan elements ----
    Seg2F x = seg2f_id();
    float vn = vnext;
#pragma unroll
    for (int j = EPT - 1; j >= 0; --j) {
        float m = mm[j];
        float ar = GAMMA_F * m, br = rr[j];
        float aa = GL_F * m;
        float delta = fmaf(GAMMA_F * vn, m, rr[j]) - vv[j];
        Seg2F e;
        e.r.A = ar; e.r.B = br; e.r.P = ar; e.r.S = br; e.r.U = ar * ar; e.r.V = ar * br; e.r.Q = br * br;
        e.a.A = aa; e.a.B = delta; e.a.P = aa; e.a.S = delta; e.a.U = aa * aa; e.a.V = aa * delta; e.a.Q = delta * delta;
        x = seg2f_compose(e, x);
        vn = vv[j];
    }
    // ordered down-reduction: lane 0 ends with composition of lanes [0,64)
#pragma unroll
    for (int s = 1; s < 64; s <<= 1) {
        Seg2F o = seg2f_shfl_down(x, s);
        x = seg2f_compose(x, o);
    }
    __shared__ Seg2F sW[4];
    if (lane == 0) sW[wv] = x;
    __syncthreads();
    if (tid == 0) {
        Seg2F t = sW[3];
        t = seg2f_compose(sW[2], t);
        t = seg2f_compose(sW[1], t);
        t = seg2f_compose(sW[0], t);
        int b4 = b * 4;
        blk[b4 + 0] = make_float4(t.r.A, t.r.B, t.r.P, t.r.S);
        blk[b4 + 1] = make_float4(t.r.U, t.r.V, t.r.Q, t.a.A);
        blk[b4 + 2] = make_float4(t.a.B, t.a.P, t.a.S, t.a.U);
        blk[b4 + 3] = make_float4(t.a.V, t.a.Q, 0.f, 0.f);
    }
}

__device__ __forceinline__ Seg2F load_seg(const float4* __restrict__ blk, int idx) {
    float4 q0 = blk[idx * 4 + 0], q1 = blk[idx * 4 + 1];
    float4 q2 = blk[idx * 4 + 2], q3 = blk[idx * 4 + 3];
    Seg2F s;
    s.r.A = q0.x; s.r.B = q0.y; s.r.P = q0.z; s.r.S = q0.w;
    s.r.U = q1.x; s.r.V = q1.y; s.r.Q = q1.z; s.a.A = q1.w;
    s.a.B = q2.x; s.a.P = q2.y; s.a.S = q2.z; s.a.U = q2.w;
    s.a.V = q3.x; s.a.Q = q3.y;
    return s;
}

// ============ K2: single-block carry scan + global stats (f32 compose, f64 finalize) ============
__global__ __launch_bounds__(NT) void k_carry(const float4* __restrict__ blk,
                                              float2* __restrict__ car,
                                              float* __restrict__ stats) {
    int tid = threadIdx.x, lane = tid & 63, wv = tid >> 6;
    Seg2F s[GPT];
#pragma unroll
    for (int p = 0; p < GPT; ++p) s[p] = load_seg(blk, tid * GPT + p);
    Seg2F gc = seg2f_id();
#pragma unroll
    for (int p = GPT - 1; p >= 0; --p) gc = seg2f_compose(s[p], gc);
    Seg2F incl = gc;
#pragma unroll
    for (int ss = 1; ss < 64; ss <<= 1) {
        Seg2F o = seg2f_shfl_down(incl, ss);
        if (lane + ss < 64) incl = seg2f_compose(incl, o);
    }
    Seg2F ex = seg2f_shfl_down(incl, 1);
    if (lane == 63) ex = seg2f_id();
    __shared__ Seg2F sW[4];
    if (lane == 0) sW[wv] = incl;
    __syncthreads();
    Seg2F tail = seg2f_id();
    for (int w = 3; w > wv; --w) tail = seg2f_compose(sW[w], tail);
    Seg2F H = seg2f_compose(ex, tail);   // composition of all summaries after this thread's group
#pragma unroll
    for (int p = GPT - 1; p >= 0; --p) {
        car[tid * GPT + p] = make_float2(H.r.B, H.a.B);   // carry entering block = H(0)
        H = seg2f_compose(s[p], H);
    }
    if (tid == 0) {
        Seg2F tot = seg2f_compose(incl, tail);   // full composition; y_in = 0
        const double Td = (double)T_N;
        double Sa = (double)tot.a.S, Qa = (double)tot.a.Q;
        double Sr = (double)tot.r.S, Qr = (double)tot.r.Q;
        double va = (Qa - Sa * Sa / Td) / (Td - 1.0);
        double vr = (Qr - Sr * Sr / Td) / (Td - 1.0);
        stats[0] = (float)(Sa / Td);
        stats[1] = (float)(1.0 / (sqrt(va) + 1e-10));
        stats[2] = (float)(Sr / Td);
        stats[3] = (float)(1.0 / (sqrt(vr) + 1e-10));
    }
}

// ============ K3: scan redo + loss from materialized ratio (all scan-layout, no LDS) ============
__global__ __launch_bounds__(NT) void k_main(const float* __restrict__ rew,
                                             const float* __restrict__ val,
                                             const int* __restrict__ msk,
                                             const float* __restrict__ rat,
                                             const float2* __restrict__ car,
                                             const float* __restrict__ stats,
                                             float2* __restrict__ lblk) {
    int tid = threadIdx.x, lane = tid & 63, wv = tid >> 6;
    int b = blockIdx.x;
    int g = b * CHUNK + tid * EPT;

    float rr[EPT], vv[EPT], mm[EPT], vnext;
    load4(rew, val, msk, g, rr, vv, mm, vnext);
    float4 q = *(const float4*)(rat + g);
    float ratj[EPT] = {q.x, q.y, q.z, q.w};
    float mean_a = stats[0], inv_a = stats[1], mean_r = stats[2], inv_r = stats[3];
    float2 c = car[b];

    Aff4 x;
    {
        x = aff_id();
        float vn = vnext;
#pragma unroll
        for (int j = EPT - 1; j >= 0; --j) {
            float m = mm[j];
            float gm = GAMMA_F * m;
            x.br = fmaf(gm, x.br, rr[j]);  x.ar = gm * x.ar;
            float delta = fmaf(GAMMA_F * vn, m, rr[j]) - vv[j];
            float gl = GL_F * m;
            x.ba = fmaf(gl, x.ba, delta);  x.aa = gl * x.aa;
            vn = vv[j];
        }
    }
    Aff4 incl = aff_wave_suffix(x, lane);
    Aff4 ex = aff_shfl_down(incl, 1);
    if (lane == 63) ex = aff_id();
    __shared__ Aff4 sW[4];
    if (lane == 0) sW[wv] = incl;
    __syncthreads();
    Aff4 tail = aff_id();
    for (int w = 3; w > wv; --w) tail = aff_compose(sW[w], tail);
    ex = aff_compose(ex, tail);
    float yr = fmaf(ex.ar, c.x, ex.br);
    float ya = fmaf(ex.aa, c.y, ex.ba);

    float aacc = 0.f, cacc = 0.f;
    float vn = vnext;
#pragma unroll
    for (int j = EPT - 1; j >= 0; --j) {
        float m = mm[j];
        float gm = GAMMA_F * m;
        yr = fmaf(gm, yr, rr[j]);                                  // ret_j
        float delta = fmaf(GAMMA_F * vn, m, rr[j]) - vv[j];
        ya = fmaf(GL_F * m, ya, delta);                            // adv_j
        vn = vv[j];
        float ratio = ratj[j];
        float rc = fminf(fmaxf(ratio, 0.8f), 1.2f);
        float an = (ya - mean_a) * inv_a;
        aacc += fminf(ratio * an, rc * an);
        float rn = (yr - mean_r) * inv_r;
        float d = vv[j] - rn;
        float adx = fabsf(d);
        cacc += (adx < 1.f) ? 0.5f * d * d : adx - 0.5f;
    }
#pragma unroll
    for (int s = 32; s > 0; s >>= 1) {
        aacc += __shfl_xor(aacc, s, 64);
        cacc += __shfl_xor(cacc, s, 64);
    }
    __shared__ float2 sL[4];
    if (lane == 0) sL[wv] = make_float2(aacc, cacc);
    __syncthreads();
    if (tid == 0) {
        lblk[b] = make_float2(sL[0].x + sL[1].x + sL[2].x + sL[3].x,
                              sL[0].y + sL[1].y + sL[2].y + sL[3].y);
    }
}

// ============ K4: final reduce ============
__global__ __launch_bounds__(NT) void k_final(const float2* __restrict__ lblk,
                                              float* __restrict__ out) {
    int tid = threadIdx.x, lane = tid & 63, wv = tid >> 6;
    double ac = 0, cr = 0;
#pragma unroll
    for (int p = 0; p < NB / NT; ++p) {
        float2 v = lblk[tid + p * NT];
        ac += v.x; cr += v.y;
    }
#pragma unroll
    for (int s = 32; s > 0; s >>= 1) {
        ac += __shfl_xor(ac, s, 64);
        cr += __shfl_xor(cr, s, 64);
    }
    __shared__ double sD[4][2];
    if (lane == 0) { sD[wv][0] = ac; sD[wv][1] = cr; }
    __syncthreads();
    if (tid == 0) {
        ac = sD[0][0] + sD[1][0] + sD[2][0] + sD[3][0];
        cr = sD[0][1] + sD[1][1] + sD[2][1] + sD[3][1];
        out[0] = (float)((-ac + cr) / (double)T_N);
    }
}

extern "C" void kernel_launch(void* const* d_in, const int* in_sizes, int n_in,
                              void* d_out, int out_size, void* d_ws, size_t ws_size,
                              hipStream_t stream) {
    const float* rew = (const float*)d_in[0];
    const float* val = (const float*)d_in[1];
    const float4* blp = (const float4*)d_in[2];
    const float4* act = (const float4*)d_in[3];
    const float4* mu  = (const float4*)d_in[4];
    const float4* lv  = (const float4*)d_in[5];
    const int*   msk = (const int*)d_in[6];

    char* ws = (char*)d_ws;
    float*  stats = (float*)ws;                        // 16 B
    float4* blk   = (float4*)(ws + 256);               // NB*64 = 131072 B
    float2* car   = (float2*)(ws + 131328);            // NB*8  =  16384 B
    float2* lblk  = (float2*)(ws + 147712);            // NB*8  =  16384 B
    float*  rat   = (float*)(ws + 164096);             // T floats = 8 MB

    k_summ <<<NB, NT, 0, stream>>>(rew, val, msk, act, mu, lv, blp, blk, rat);
    k_carry<<<1,  NT, 0, stream>>>(blk, car, stats);
    k_main <<<NB, NT, 0, stream>>>(rew, val, msk, rat, car, stats, lblk);
    k_final<<<1,  NT, 0, stream>>>(lblk, (float*)d_out);
}